// Round 1
// baseline (3104.161 us; speedup 1.0000x reference)
//
#include <hip/hip_runtime.h>

typedef unsigned int uint;
typedef unsigned short ushort;
typedef __attribute__((ext_vector_type(4))) float f4;
typedef __attribute__((ext_vector_type(8))) short bf8;

#define T_ 256
#define B_ 64
#define E_ 256
#define HD_ 256
#define G4_ 1024
#define NTAG 20

// ---- workspace layout (float offsets) ----
#define GX_OFF 0ull           // gx [2][256][64][1024]  (33,554,432 f)
#define HF_OFF 33554432ull    // histF [256][64][256]
#define HB_OFF 37748736ull    // histB [256][64][256]  (backward-step order)
#define LG_OFF 41943040ull    // logits [256][64][20]
#define CS_OFF 42270720ull    // c state [2][64][256]
#define Q_OFFF 42303488ull    // ushort (bf16-bits) area starts here

// ---- q (ushort) offsets ----
#define WHHF_HI 0u
#define WHHB_HI 524288u
#define WIHF_HI 1048576u
#define WIHB_HI 1572864u
#define LO_D    262144u       // lo = hi + LO_D for the 4 weight matrices
#define WL_HI   2097152u
#define WL_LO   2107392u

__device__ __forceinline__ ushort f2bf(float x){
  uint u = __float_as_uint(x);
  uint r = (u + 0x7fffu + ((u >> 16) & 1u)) >> 16;
  return (ushort)r;
}
__device__ __forceinline__ float bf2f(ushort h){ return __uint_as_float(((uint)h) << 16); }
__device__ __forceinline__ void splitf(float x, ushort &h, ushort &l){
  h = f2bf(x);
  l = f2bf(x - bf2f(h));
}
__device__ __forceinline__ f4 mfma16(bf8 a, bf8 b, f4 c){
  return __builtin_amdgcn_mfma_f32_16x16x32_bf16(a, b, c, 0, 0, 0);
}
__device__ __forceinline__ float sigm(float x){ return 1.0f / (1.0f + expf(-x)); }

// ============ K0: split weights into bf16 hi/lo ============
__global__ void k0_split(const float* __restrict__ whhF, const float* __restrict__ whhB,
                         const float* __restrict__ wihF, const float* __restrict__ wihB,
                         const float* __restrict__ wl, ushort* __restrict__ q){
  uint stride = gridDim.x * blockDim.x;
  for (uint i = blockIdx.x * blockDim.x + threadIdx.x; i < 1058816u; i += stride){
    float x; uint hbase;
    if (i < 262144u){ x = whhF[i]; hbase = WHHF_HI + i; }
    else if (i < 524288u){ x = whhB[i - 262144u]; hbase = WHHB_HI + (i - 262144u); }
    else if (i < 786432u){ x = wihF[i - 524288u]; hbase = WIHF_HI + (i - 524288u); }
    else if (i < 1048576u){ x = wihB[i - 786432u]; hbase = WIHB_HI + (i - 786432u); }
    else {
      uint j = i - 1048576u; // < 10240
      ushort h, l; splitf(wl[j], h, l);
      q[WL_HI + j] = h; q[WL_LO + j] = l;
      continue;
    }
    ushort h, l; splitf(x, h, l);
    q[hbase] = h; q[hbase + LO_D] = l;
  }
}

// ============ K1: gx = x @ WihT + bih + bhh  (both dirs; dir1 uses reversed time) ============
__global__ __launch_bounds__(256) void k1_gx(const int* __restrict__ sents,
    const float* __restrict__ emb, const ushort* __restrict__ q,
    const float* __restrict__ bihF, const float* __restrict__ bhhF,
    const float* __restrict__ bihB, const float* __restrict__ bhhB,
    float* __restrict__ gx)
{
  __shared__ ushort Bs[2][64][256]; // exactly 64 KiB, XOR-swizzled 16B chunks
  const int tid = threadIdx.x;
  const int dir = blockIdx.z;
  const int n0 = blockIdx.x * 64;
  const int r0 = blockIdx.y * 64;
  const ushort* whi = q + (dir ? WIHB_HI : WIHF_HI);

  for (int cid = tid; cid < 4096; cid += 256){
    int half = cid >> 11;
    int c = (cid >> 5) & 63;
    int kc = cid & 31;
    const ushort* src = whi + half * LO_D + (size_t)(n0 + c) * 256 + kc * 8;
    uint4 v = *(const uint4*)src;
    *(uint4*)&Bs[half][c][(kc ^ (c & 31)) * 8] = v;
  }
  __syncthreads();

  const int w = tid >> 6, l = tid & 63;
  const int lrow = l & 15, lk8 = (l >> 4) * 8;
  const int r = r0 + w * 16 + lrow;
  const int t = r >> 6, b = r & 63;
  const int tok = sents[b * T_ + (dir ? (T_ - 1 - t) : t)];
  const float* arow = emb + (size_t)tok * E_;

  f4 acc[4];
  #pragma unroll
  for (int i = 0; i < 4; i++){ acc[i][0]=0.f; acc[i][1]=0.f; acc[i][2]=0.f; acc[i][3]=0.f; }

  for (int ks = 0; ks < 8; ks++){
    const float* ap = arow + ks * 32 + lk8;
    f4 v0 = *(const f4*)ap;
    f4 v1 = *(const f4*)(ap + 4);
    bf8 ah, al;
    #pragma unroll
    for (int j = 0; j < 4; j++){
      ushort hh, ll;
      splitf(v0[j], hh, ll); ah[j] = (short)hh; al[j] = (short)ll;
      splitf(v1[j], hh, ll); ah[4 + j] = (short)hh; al[4 + j] = (short)ll;
    }
    const int kc = ks * 4 + (l >> 4);
    #pragma unroll
    for (int nt = 0; nt < 4; nt++){
      const int c = nt * 16 + lrow;
      const int skc = kc ^ (c & 31);
      bf8 bh = *(const bf8*)&Bs[0][c][skc * 8];
      bf8 blo = *(const bf8*)&Bs[1][c][skc * 8];
      acc[nt] = mfma16(ah, bh, acc[nt]);
      acc[nt] = mfma16(ah, blo, acc[nt]);
      acc[nt] = mfma16(al, bh, acc[nt]);
    }
  }

  const float* bih = dir ? bihB : bihF;
  const float* bhh = dir ? bhhB : bhhF;
  const size_t gbase = (size_t)dir * 16777216ull;
  #pragma unroll
  for (int nt = 0; nt < 4; nt++){
    int col = n0 + nt * 16 + lrow;
    float bias = bih[col] + bhh[col];
    #pragma unroll
    for (int reg = 0; reg < 4; reg++){
      int row = r0 + w * 16 + (l >> 4) * 4 + reg;
      gx[gbase + (size_t)row * 1024 + col] = acc[nt][reg] + bias;
    }
  }
}

// ============ K2: one LSTM step (both dirs). block = (unit-group of 16, dir) ============
__global__ __launch_bounds__(256) void k2_step(const ushort* __restrict__ q,
    const float* __restrict__ gx, float* __restrict__ histF, float* __restrict__ histB,
    const float* __restrict__ h0, const float* __restrict__ c0,
    float* __restrict__ cst, const int t)
{
  __shared__ ushort Bs[2][64][256];
  const int tid = threadIdx.x;
  const int dir = blockIdx.y;
  const int u0 = blockIdx.x * 16;
  const ushort* whi = q + (dir ? WHHB_HI : WHHF_HI);

  for (int cid = tid; cid < 4096; cid += 256){
    int half = cid >> 11;
    int c = (cid >> 5) & 63;
    int kc = cid & 31;
    int grow = (c >> 4) * 256 + u0 + (c & 15); // gate-strided rows
    const ushort* src = whi + half * LO_D + (size_t)grow * 256 + kc * 8;
    uint4 v = *(const uint4*)src;
    *(uint4*)&Bs[half][c][(kc ^ (c & 31)) * 8] = v;
  }
  __syncthreads();

  float* hist = dir ? histB : histF;
  const float* hprev = (t == 0) ? (h0 + dir * 16384) : (hist + (size_t)(t - 1) * 16384);
  const int w = tid >> 6, l = tid & 63;
  const int lrow = l & 15, lk8 = (l >> 4) * 8;
  const int arow = w * 16 + lrow;

  f4 acc[4];
  #pragma unroll
  for (int i = 0; i < 4; i++){ acc[i][0]=0.f; acc[i][1]=0.f; acc[i][2]=0.f; acc[i][3]=0.f; }

  for (int ks = 0; ks < 8; ks++){
    const float* ap = hprev + arow * 256 + ks * 32 + lk8;
    f4 v0 = *(const f4*)ap;
    f4 v1 = *(const f4*)(ap + 4);
    bf8 ah, al;
    #pragma unroll
    for (int j = 0; j < 4; j++){
      ushort hh, ll;
      splitf(v0[j], hh, ll); ah[j] = (short)hh; al[j] = (short)ll;
      splitf(v1[j], hh, ll); ah[4 + j] = (short)hh; al[4 + j] = (short)ll;
    }
    const int kc = ks * 4 + (l >> 4);
    #pragma unroll
    for (int nt = 0; nt < 4; nt++){
      const int c = nt * 16 + lrow;
      const int skc = kc ^ (c & 31);
      bf8 bh = *(const bf8*)&Bs[0][c][skc * 8];
      bf8 blo = *(const bf8*)&Bs[1][c][skc * 8];
      acc[nt] = mfma16(ah, bh, acc[nt]);
      acc[nt] = mfma16(ah, blo, acc[nt]);
      acc[nt] = mfma16(al, bh, acc[nt]);
    }
  }

  // epilogue: all 4 gates for (row, unit) are lane-local (acc[gate][reg])
  const int unit = u0 + lrow;
  const size_t gxb = (size_t)dir * 16777216ull + (size_t)t * 65536ull;
  const size_t cb = (size_t)dir * 16384ull;
  #pragma unroll
  for (int reg = 0; reg < 4; reg++){
    int row = w * 16 + (l >> 4) * 4 + reg;
    float g0 = acc[0][reg] + gx[gxb + (size_t)row * 1024 + 0   + unit];
    float g1 = acc[1][reg] + gx[gxb + (size_t)row * 1024 + 256 + unit];
    float g2 = acc[2][reg] + gx[gxb + (size_t)row * 1024 + 512 + unit];
    float g3 = acc[3][reg] + gx[gxb + (size_t)row * 1024 + 768 + unit];
    float co = (t == 0) ? c0[cb + (size_t)row * 256 + unit] : cst[cb + (size_t)row * 256 + unit];
    float ig = sigm(g0), fg = sigm(g1), gg = tanhf(g2), og = sigm(g3);
    float cn = fg * co + ig * gg;
    float hn = og * tanhf(cn);
    cst[cb + (size_t)row * 256 + unit] = cn;
    hist[(size_t)t * 16384 + (size_t)row * 256 + unit] = hn;
  }
}

// ============ K3: logits = [hf|hb] @ WlT + bl (MFMA, N padded to 32) ============
__global__ __launch_bounds__(256) void k3_logits(const ushort* __restrict__ q,
    const float* __restrict__ histF, const float* __restrict__ histB,
    const float* __restrict__ bl, float* __restrict__ logits)
{
  __shared__ ushort Bs[2][32][512];
  const int tid = threadIdx.x;
  const int r0 = blockIdx.x * 64;

  for (int cid = tid; cid < 4096; cid += 256){
    int half = cid >> 11;
    int c = (cid >> 6) & 31;
    int kc = cid & 63;
    uint4 v; v.x = 0; v.y = 0; v.z = 0; v.w = 0;
    if (c < NTAG){
      const ushort* src = q + (half ? WL_LO : WL_HI) + (size_t)c * 512 + kc * 8;
      v = *(const uint4*)src;
    }
    *(uint4*)&Bs[half][c][(kc ^ (c & 31)) * 8] = v;
  }
  __syncthreads();

  const int w = tid >> 6, l = tid & 63;
  const int lrow = l & 15, lk8 = (l >> 4) * 8;
  const int r = r0 + w * 16 + lrow;
  const int t = r >> 6, b = r & 63;

  f4 acc[2];
  #pragma unroll
  for (int i = 0; i < 2; i++){ acc[i][0]=0.f; acc[i][1]=0.f; acc[i][2]=0.f; acc[i][3]=0.f; }

  for (int ks = 0; ks < 16; ks++){
    int k = ks * 32 + lk8;
    const float* ap = (k < 256)
      ? (histF + ((size_t)t * 64 + b) * 256 + k)
      : (histB + ((size_t)(255 - t) * 64 + b) * 256 + (k - 256));
    f4 v0 = *(const f4*)ap;
    f4 v1 = *(const f4*)(ap + 4);
    bf8 ah, al;
    #pragma unroll
    for (int j = 0; j < 4; j++){
      ushort hh, ll;
      splitf(v0[j], hh, ll); ah[j] = (short)hh; al[j] = (short)ll;
      splitf(v1[j], hh, ll); ah[4 + j] = (short)hh; al[4 + j] = (short)ll;
    }
    int kc = k >> 3;
    #pragma unroll
    for (int nt = 0; nt < 2; nt++){
      int c = nt * 16 + lrow;
      int skc = kc ^ (c & 31);
      bf8 bh = *(const bf8*)&Bs[0][c][skc * 8];
      bf8 blo = *(const bf8*)&Bs[1][c][skc * 8];
      acc[nt] = mfma16(ah, bh, acc[nt]);
      acc[nt] = mfma16(ah, blo, acc[nt]);
      acc[nt] = mfma16(al, bh, acc[nt]);
    }
  }

  #pragma unroll
  for (int nt = 0; nt < 2; nt++){
    int tag = nt * 16 + lrow;
    if (tag < NTAG){
      float bias = bl[tag];
      #pragma unroll
      for (int reg = 0; reg < 4; reg++){
        int row = r0 + w * 16 + (l >> 4) * 4 + reg;
        logits[(size_t)row * NTAG + tag] = acc[nt][reg] + bias;
      }
    }
  }
}

// ============ K4: Viterbi DP + backtrace + probs + scores (one block per batch) ============
__global__ __launch_bounds__(64) void k4_viterbi(const float* __restrict__ logits,
    const float* __restrict__ trans, float* __restrict__ out)
{
  const int b = blockIdx.x, tid = threadIdx.x;
  __shared__ float tr[NTAG][NTAG];
  __shared__ float trell[T_][NTAG];
  __shared__ unsigned char bp[T_][NTAG];
  __shared__ int path[T_];
  __shared__ float cur[NTAG], nv[NTAG];

  for (int i = tid; i < NTAG * NTAG; i += 64) tr[i / NTAG][i % NTAG] = trans[i];
  if (tid < NTAG){
    float v = logits[(size_t)b * NTAG + tid];
    cur[tid] = v; trell[0][tid] = v;
  }
  __syncthreads();

  for (int t = 1; t < T_; t++){
    if (tid < NTAG){
      float best = -3.0e38f; int bi = 0;
      #pragma unroll
      for (int p = 0; p < NTAG; p++){
        float v = cur[p] + tr[p][tid];
        if (v > best){ best = v; bi = p; }   // first-max (strict >)
      }
      float nvv = logits[((size_t)t * 64 + b) * NTAG + tid] + best;
      nv[tid] = nvv; trell[t][tid] = nvv; bp[t][tid] = (unsigned char)bi;
    }
    __syncthreads();
    if (tid < NTAG) cur[tid] = nv[tid];
    __syncthreads();
  }

  if (tid == 0){
    float best = -3.0e38f; int bi = 0;
    for (int c = 0; c < NTAG; c++){
      if (trell[T_ - 1][c] > best){ best = trell[T_ - 1][c]; bi = c; }
    }
    out[b] = best;                 // scores
    path[T_ - 1] = bi;
    for (int t = T_ - 1; t >= 1; t--) path[t - 1] = bp[t][path[t]];
  }
  __syncthreads();

  for (int t = tid; t < T_; t += 64){
    float m = -3.0e38f;
    for (int c = 0; c < NTAG; c++) m = fmaxf(m, trell[t][c]);
    float s = 0.f;
    for (int c = 0; c < NTAG; c++) s += expf(trell[t][c] - m);
    float p = expf(trell[t][path[t]] - m) / s;
    out[64 + (size_t)b * T_ + t] = (float)path[t];          // path.T
    out[64 + 64 * T_ + (size_t)b * T_ + t] = p;             // probs.T
  }
}

extern "C" void kernel_launch(void* const* d_in, const int* in_sizes, int n_in,
                              void* d_out, int out_size, void* d_ws, size_t ws_size,
                              hipStream_t stream){
  (void)in_sizes; (void)n_in; (void)out_size; (void)ws_size;
  const int*   sents = (const int*)d_in[0];
  const float* emb   = (const float*)d_in[1];
  const float* wihF  = (const float*)d_in[2];
  const float* whhF  = (const float*)d_in[3];
  const float* bihF  = (const float*)d_in[4];
  const float* bhhF  = (const float*)d_in[5];
  const float* wihB  = (const float*)d_in[6];
  const float* whhB  = (const float*)d_in[7];
  const float* bihB  = (const float*)d_in[8];
  const float* bhhB  = (const float*)d_in[9];
  const float* wl    = (const float*)d_in[10];
  const float* bl    = (const float*)d_in[11];
  const float* trans = (const float*)d_in[12];
  const float* h0    = (const float*)d_in[13];
  const float* c0    = (const float*)d_in[14];

  float* wsf    = (float*)d_ws;
  ushort* q     = (ushort*)(wsf + Q_OFFF);
  float* gx     = wsf + GX_OFF;
  float* histF  = wsf + HF_OFF;
  float* histB  = wsf + HB_OFF;
  float* logits = wsf + LG_OFF;
  float* cst    = wsf + CS_OFF;
  float* out    = (float*)d_out;

  k0_split<<<1024, 256, 0, stream>>>(whhF, whhB, wihF, wihB, wl, q);
  k1_gx<<<dim3(16, 256, 2), 256, 0, stream>>>(sents, emb, q, bihF, bhhF, bihB, bhhB, gx);
  for (int t = 0; t < T_; t++)
    k2_step<<<dim3(16, 2), 256, 0, stream>>>(q, gx, histF, histB, h0, c0, cst, t);
  k3_logits<<<256, 256, 0, stream>>>(q, histF, histB, bl, logits);
  k4_viterbi<<<64, 64, 0, stream>>>(logits, trans, out);
}